// Round 11
// baseline (5955.009 us; speedup 1.0000x reference)
//
#include <hip/hip_runtime.h>
#include <math.h>

#define BATCH 256
#define DIN 512
#define DFEAT 512
#define HSZ 512
#define VOCAB 32000
#define EMB 64
#define SLEN 16
#define NTILE 500          // VOCAB / 64 col-tiles
#define MARGIN 0.0625f

typedef __attribute__((ext_vector_type(8))) short bf16x8;
typedef __attribute__((ext_vector_type(4))) float f32x4;

__device__ inline unsigned bf16_rne(float x) {
    union { float f; unsigned u; } u; u.f = x;
    unsigned r = u.u + 0x7fff + ((u.u >> 16) & 1);
    return r >> 16;
}

// ---------- fp32 SMEM GEMM (prologue): C = A @ W^T (+bias) ----------
template<int BM, int BN, int BK, int TM, int TN>
__global__ __launch_bounds__(256) void gemm_atb(
    const float* __restrict__ A,
    const float* __restrict__ W,
    const float* __restrict__ bias,
    float* __restrict__ C, long long ldc,
    int M, int N, int K)
{
    __shared__ float As[BK][BM + 4];
    __shared__ float Bs[BK][BN + 4];
    constexpr int THREADS = (BM / TM) * (BN / TN);
    const int tid = threadIdx.x;
    const int tx = tid % (BN / TN);
    const int ty = tid / (BN / TN);
    const int row0 = blockIdx.y * BM;
    const int col0 = blockIdx.x * BN;
    float acc[TM][TN] = {};
    for (int k0 = 0; k0 < K; k0 += BK) {
        for (int i = tid; i < BM * BK; i += THREADS) {
            int m = i / BK, k = i % BK;
            As[k][m] = A[(long long)(row0 + m) * K + k0 + k];
        }
        for (int i = tid; i < BN * BK; i += THREADS) {
            int n = i / BK, k = i % BK;
            Bs[k][n] = W[(long long)(col0 + n) * K + k0 + k];
        }
        __syncthreads();
        #pragma unroll
        for (int kk = 0; kk < BK; ++kk) {
            float a[TM], b[TN];
            #pragma unroll
            for (int i = 0; i < TM; ++i) a[i] = As[kk][ty * TM + i];
            #pragma unroll
            for (int j = 0; j < TN; ++j) b[j] = Bs[kk][tx * TN + j];
            #pragma unroll
            for (int i = 0; i < TM; ++i)
                #pragma unroll
                for (int j = 0; j < TN; ++j)
                    acc[i][j] = fmaf(a[i], b[j], acc[i][j]);
        }
        __syncthreads();
    }
    #pragma unroll
    for (int i = 0; i < TM; ++i) {
        long long m = row0 + ty * TM + i;
        float* crow = C + m * ldc;
        #pragma unroll
        for (int j = 0; j < TN; ++j) {
            int n = col0 + tx * TN + j;
            float v = acc[i][j];
            if (bias) v += bias[n];
            crow[n] = v;
        }
    }
}

// ---------- fused prologue: Wb cast, Wcat2/bcat2 build, flag reset ----------
__global__ void prep_kernel(const float* __restrict__ out_W, ushort* __restrict__ Wb,
                            const float* __restrict__ W_ih, const float* __restrict__ W_hh,
                            const float* __restrict__ b_ih, const float* __restrict__ b_hh,
                            float* __restrict__ Wcat2, float* __restrict__ bcat2,
                            int* __restrict__ flags)
{
    const int stride = gridDim.x * 256;
    const int t0 = blockIdx.x * 256 + threadIdx.x;
    for (int i = t0; i < VOCAB * HSZ / 4; i += stride) {
        const float4 v = ((const float4*)out_W)[i];
        ushort4 o;
        o.x = (ushort)bf16_rne(v.x); o.y = (ushort)bf16_rne(v.y);
        o.z = (ushort)bf16_rne(v.z); o.w = (ushort)bf16_rne(v.w);
        ((ushort4*)Wb)[i] = o;
    }
    for (long long i = t0; i < 2048LL * 576; i += stride) {
        int g = (int)(i / 576), k = (int)(i % 576);
        int j = g >> 2, comp = g & 3;
        float v;
        if (comp == 0)      v = (k < 64) ? W_ih[j * 64 + k]          : W_hh[(long long)j * 512 + k - 64];
        else if (comp == 1) v = (k < 64) ? W_ih[(512 + j) * 64 + k]  : W_hh[(long long)(512 + j) * 512 + k - 64];
        else if (comp == 2) v = (k < 64) ? W_ih[(1024 + j) * 64 + k] : 0.f;
        else                v = (k < 64) ? 0.f                        : W_hh[(long long)(1024 + j) * 512 + k - 64];
        Wcat2[i] = v;
    }
    for (int i = t0; i < 2048; i += stride) {
        int j = i >> 2, comp = i & 3;
        float bv = (comp == 0) ? b_ih[j] + b_hh[j]
                 : (comp == 1) ? b_ih[512 + j] + b_hh[512 + j]
                 : (comp == 2) ? b_ih[1024 + j] : b_hh[1024 + j];
        bcat2[i] = bv;
    }
    for (int i = t0; i < BATCH; i += stride) flags[i] = 0;   // replay-safe token reset
}

// ---------- AG: producer-consumer {argmax(t-1) on 64 blocks} + {G on 512 blocks} ----------
template<bool FIRST>
__global__ __launch_bounds__(256) void ag_kernel(
    const float* __restrict__ hprev, float* __restrict__ hnew,
    const float* __restrict__ Wcat2, const float* __restrict__ bcat2,
    float* __restrict__ ebuf, const float* __restrict__ sos,
    ushort* __restrict__ hbf,
    const float* __restrict__ tmaxv, const float* __restrict__ lprev,
    const float* __restrict__ out_W, const float* __restrict__ out_b,
    const float* __restrict__ emb, float* __restrict__ seq,
    int* __restrict__ flags, int token, int tprev)
{
    const int tid = threadIdx.x;
    const int lane = tid & 63, wave = tid >> 6;

    if (blockIdx.x < 64) {
        // ===== producer: argmax for rows blk*4 .. blk*4+3 (one wave per row) =====
        if (FIRST) return;
        __shared__ int s_qt[4][32];
        __shared__ int s_cc[4][32];
        __shared__ int s_qn[4];
        __shared__ int s_cn[4];
        if (tid < 4) { s_qn[tid] = 0; s_cn[tid] = 0; }
        __syncthreads();
        const int r = blockIdx.x * 4 + wave;
        const float* trow = tmaxv + (long long)r * 512;
        float tv[8];
        float m = -INFINITY;
        #pragma unroll
        for (int s = 0; s < 8; ++s) {
            int i = lane + (s << 6);
            tv[s] = (i < NTILE) ? trow[i] : -INFINITY;
            m = fmaxf(m, tv[s]);
        }
        #pragma unroll
        for (int d = 32; d; d >>= 1) m = fmaxf(m, __shfl_xor(m, d, 64));
        const float thr = m - MARGIN;
        #pragma unroll
        for (int s = 0; s < 8; ++s) {
            int i = lane + (s << 6);
            if (i < NTILE && tv[s] >= thr) {
                int sl = atomicAdd(&s_qn[wave], 1);
                if (sl < 32) s_qt[wave][sl] = i;
            }
        }
        int nq = min(s_qn[wave], 32);
        const float* lrow = lprev + (long long)r * (SLEN * (long long)VOCAB);
        for (int q = 0; q < nq; ++q) {
            float v = lrow[s_qt[wave][q] * 64 + lane];
            if (v >= thr) {
                int sl = atomicAdd(&s_cn[wave], 1);
                if (sl < 32) s_cc[wave][sl] = s_qt[wave][q] * 64 + lane;
            }
        }
        int nc = min(s_cn[wave], 32);
        const float* hrow = hprev + (long long)r * 512;
        float bv = -INFINITY; int bsym = 0x7fffffff;
        for (int ci = 0; ci < nc; ++ci) {
            int cc = s_cc[wave][ci];
            const float* wrow = out_W + (long long)cc * 512;
            float s = 0.f;
            for (int k = lane; k < 512; k += 64) s = fmaf(hrow[k], wrow[k], s);
            #pragma unroll
            for (int off = 32; off; off >>= 1) s += __shfl_down(s, off, 64);
            if (lane == 0) {
                float x = s + out_b[cc];
                if (x > bv || (x == bv && cc < bsym)) { bv = x; bsym = cc; }
            }
        }
        int sym = __shfl(bsym, 0, 64);
        if (sym < 0 || sym >= VOCAB) sym = 0;   // crash-proofing
        if (lane == 0) seq[r * SLEN + tprev] = (float)sym;
        __hip_atomic_store(&ebuf[(long long)r * EMB + lane],
                           emb[(long long)sym * EMB + lane],
                           __ATOMIC_RELAXED, __HIP_MEMORY_SCOPE_AGENT);
        __threadfence();   // wave-wide vmcnt drain: all 64 ebuf stores complete
        if (lane == 0)
            __hip_atomic_store(&flags[r], token, __ATOMIC_RELEASE, __HIP_MEMORY_SCOPE_AGENT);
        return;
    }

    // ===== consumer: G tile (identical math to validated round-10 kernel) =====
    __shared__ __align__(16) char smem[22528];
    const int blk = blockIdx.x - 64;
    const int ty = blk >> 5;            // 16-row batch group
    const int tx = blk & 31;            // col group (16 j x 4 comps)
    float* As = (float*)smem;                    // [64][18]
    float* Bs = (float*)(smem + 4608);           // [64][68]
    const int tyt = tid >> 4;
    const int txt = tid & 15;

    if (!FIRST) {
        if (tid < 16) {
            while (__hip_atomic_load(&flags[ty * 16 + tid],
                                     __ATOMIC_ACQUIRE, __HIP_MEMORY_SCOPE_AGENT) < token)
                __builtin_amdgcn_s_sleep(2);
        }
        __syncthreads();
    }

    float acc[4] = {};
    for (int k0 = 0; k0 < 576; k0 += 64) {
        for (int i = tid; i < 16 * 64; i += 256) {
            int m = i >> 6, k = i & 63;
            int kc = k0 + k;
            float v;
            if (kc < 64) {
                if (FIRST) v = sos[kc];
                else v = __hip_atomic_load(&ebuf[(long long)(ty * 16 + m) * EMB + kc],
                                           __ATOMIC_RELAXED, __HIP_MEMORY_SCOPE_AGENT);
            } else {
                v = hprev[(long long)(ty * 16 + m) * 512 + kc - 64];
            }
            As[k * 18 + m] = v;
        }
        for (int i = tid; i < 64 * 64; i += 256) {
            int n = i >> 6, k = i & 63;
            Bs[k * 68 + n] = Wcat2[(long long)(tx * 64 + n) * 576 + k0 + k];
        }
        __syncthreads();
        #pragma unroll 8
        for (int kk = 0; kk < 64; ++kk) {
            const float a = As[kk * 18 + tyt];
            const float4 b = *(const float4*)&Bs[kk * 68 + txt * 4];
            acc[0] = fmaf(a, b.x, acc[0]);
            acc[1] = fmaf(a, b.y, acc[1]);
            acc[2] = fmaf(a, b.z, acc[2]);
            acc[3] = fmaf(a, b.w, acc[3]);
        }
        __syncthreads();
    }
    float* gt = (float*)smem;            // [16][64] reuse
    #pragma unroll
    for (int j = 0; j < 4; ++j)
        gt[tyt * 64 + txt * 4 + j] = acc[j];
    __syncthreads();
    {
        int row = tid >> 4, jl = tid & 15;
        int jg = tx * 16 + jl;
        float gr  = gt[row * 64 + jl * 4 + 0] + bcat2[jg * 4 + 0];
        float gz  = gt[row * 64 + jl * 4 + 1] + bcat2[jg * 4 + 1];
        float gni = gt[row * 64 + jl * 4 + 2] + bcat2[jg * 4 + 2];
        float gnh = gt[row * 64 + jl * 4 + 3] + bcat2[jg * 4 + 3];
        float r = 1.0f / (1.0f + expf(-gr));
        float z = 1.0f / (1.0f + expf(-gz));
        float n = tanhf(gni + r * gnh);
        long long bglob = ty * 16 + row;
        float hold = hprev[bglob * 512 + jg];
        float h = (1.0f - z) * n + z * hold;
        hnew[bglob * 512 + jg] = h;
        hbf[bglob * 512 + jg] = (ushort)bf16_rne(h);
    }
}

// ---------- L: logits MFMA, BM=128 x BN=64, 1000 blocks, XCD-swizzled (round-10) ----------
__global__ __launch_bounds__(256) void logits_bm128_kernel(
    const ushort* __restrict__ hbf,
    const ushort* __restrict__ Wb,
    const float* __restrict__ out_b,
    float* __restrict__ lbase, float* __restrict__ tmaxv)
{
    __shared__ __align__(16) char As[16384];
    __shared__ __align__(16) char Bs[8192];
    __shared__ float s_mv[128];
    const int tid = threadIdx.x;
    const int lane = tid & 63;
    const int wave = tid >> 6;
    const int bid = blockIdx.x;
    const int job = (bid & 7) * 125 + (bid >> 3);
    const int jx = job >> 1;
    const int jy = job & 1;
    const int row0 = jy * 128;
    const int col0 = jx * 64;

    f32x4 acc[2][4] = {};
    const int srow = tid >> 3;
    const int sch = tid & 7;

    for (int k0 = 0; k0 < 512; k0 += 64) {
        #pragma unroll
        for (int ra = 0; ra < 4; ++ra) {
            int row = ra * 32 + srow;
            const char* g = (const char*)(hbf + (long long)(row0 + row) * 512 + k0) + ((sch ^ (row & 7)) * 16);
            __builtin_amdgcn_global_load_lds(
                (const __attribute__((address_space(1))) void*)g,
                (__attribute__((address_space(3))) void*)(As + row * 128 + sch * 16), 16, 0, 0);
        }
        #pragma unroll
        for (int rb = 0; rb < 2; ++rb) {
            int row = rb * 32 + srow;
            const char* g = (const char*)(Wb + (long long)(col0 + row) * 512 + k0) + ((sch ^ (row & 7)) * 16);
            __builtin_amdgcn_global_load_lds(
                (const __attribute__((address_space(1))) void*)g,
                (__attribute__((address_space(3))) void*)(Bs + row * 128 + sch * 16), 16, 0, 0);
        }
        __syncthreads();
        #pragma unroll
        for (int k32 = 0; k32 < 64; k32 += 32) {
            bf16x8 af[2], bfr[4];
            #pragma unroll
            for (int f = 0; f < 2; ++f) {
                int rA = wave * 32 + f * 16 + (lane & 15);
                int byteA = (rA * 128 + (k32 + ((lane >> 4) << 3)) * 2) ^ ((rA & 7) << 4);
                af[f] = *(const bf16x8*)&As[byteA];
            }
            #pragma unroll
            for (int j = 0; j < 4; ++j) {
                int rB = j * 16 + (lane & 15);
                int byteB = (rB * 128 + (k32 + ((lane >> 4) << 3)) * 2) ^ ((rB & 7) << 4);
                bfr[j] = *(const bf16x8*)&Bs[byteB];
            }
            #pragma unroll
            for (int f = 0; f < 2; ++f)
                #pragma unroll
                for (int j = 0; j < 4; ++j)
                    acc[f][j] = __builtin_amdgcn_mfma_f32_16x16x32_bf16(af[f], bfr[j], acc[f][j], 0, 0, 0);
        }
        __syncthreads();
    }

    #pragma unroll
    for (int f = 0; f < 2; ++f) {
        #pragma unroll
        for (int q = 0; q < 4; ++q) {
            int r_local = wave * 32 + f * 16 + ((lane >> 4) << 2) + q;
            float* crow = lbase + (long long)(row0 + r_local) * (SLEN * (long long)VOCAB);
            float mv = -INFINITY;
            #pragma unroll
            for (int j = 0; j < 4; ++j) {
                int c = col0 + j * 16 + (lane & 15);
                float v = acc[f][j][q] + out_b[c];
                __builtin_nontemporal_store(v, &crow[c]);
                mv = fmaxf(mv, v);
            }
            #pragma unroll
            for (int m = 1; m < 16; m <<= 1) mv = fmaxf(mv, __shfl_xor(mv, m, 64));
            if ((lane & 15) == 0) s_mv[r_local] = mv;
        }
    }
    __syncthreads();
    if (tid < 128)
        tmaxv[(long long)(row0 + tid) * 512 + jx] = s_mv[tid];
}

// ---------- final argmax (round-10 validated) ----------
__global__ __launch_bounds__(256) void argmax_kernel(
    const float* __restrict__ tmaxv, const float* __restrict__ lbase,
    const float* __restrict__ h, const float* __restrict__ out_W,
    const float* __restrict__ out_b, const float* __restrict__ emb,
    float* __restrict__ seq, float* __restrict__ ebuf, int t)
{
    __shared__ float s_red[256];
    __shared__ int s_qt[64];
    __shared__ int s_cand[64];
    __shared__ float s_rv[64];
    __shared__ int s_cnt2[2];
    __shared__ int s_sym;
    const int b = blockIdx.x;
    const int tid = threadIdx.x;
    const int lane = tid & 63, wave = tid >> 6;
    const float* row = lbase + (long long)b * (SLEN * (long long)VOCAB);

    float v0 = tmaxv[(long long)b * 512 + tid];
    float v1 = (tid + 256 < NTILE) ? tmaxv[(long long)b * 512 + 256 + tid] : -INFINITY;
    s_red[tid] = fmaxf(v0, v1); __syncthreads();
    for (int s = 128; s > 0; s >>= 1) {
        if (tid < s) s_red[tid] = fmaxf(s_red[tid], s_red[tid + s]);
        __syncthreads();
    }
    float M = s_red[0];
    if (tid == 0) { s_cnt2[0] = 0; s_cnt2[1] = 0; }
    __syncthreads();
    if (v0 >= M - MARGIN) {
        int s = atomicAdd(&s_cnt2[0], 1);
        if (s < 64) s_qt[s] = tid;
    }
    if (v1 >= M - MARGIN) {
        int s = atomicAdd(&s_cnt2[0], 1);
        if (s < 64) s_qt[s] = tid + 256;
    }
    __syncthreads();
    int nq = min(s_cnt2[0], 64);
    for (int idx = tid; idx < nq * 64; idx += 256) {
        int c = s_qt[idx >> 6] * 64 + (idx & 63);
        if (row[c] >= M - MARGIN) {
            int s = atomicAdd(&s_cnt2[1], 1);
            if (s < 64) s_cand[s] = c;
        }
    }
    __syncthreads();
    int nc = min(s_cnt2[1], 64);
    const float* hrow = h + (long long)b * 512;
    for (int ci = wave; ci < nc; ci += 4) {
        int vv = s_cand[ci];
        const float* wrow = out_W + (long long)vv * 512;
        float s = 0.f;
        for (int k = lane; k < 512; k += 64) s = fmaf(hrow[k], wrow[k], s);
        for (int off = 32; off > 0; off >>= 1) s += __shfl_down(s, off, 64);
        if (lane == 0) s_rv[ci] = s + out_b[vv];
    }
    __syncthreads();
    if (tid == 0) {
        float bv = -INFINITY; int sym = 0x7fffffff;
        for (int ci = 0; ci < nc; ++ci) {
            float xx = s_rv[ci]; int c = s_cand[ci];
            if (xx > bv || (xx == bv && c < sym)) { bv = xx; sym = c; }
        }
        if (sym < 0 || sym >= VOCAB) sym = 0;
        seq[b * SLEN + t] = (float)sym;
        s_sym = sym;
    }
    __syncthreads();
    if (tid < EMB) ebuf[(long long)b * EMB + tid] = emb[(long long)s_sym * EMB + tid];
}

extern "C" void kernel_launch(void* const* d_in, const int* in_sizes, int n_in,
                              void* d_out, int out_size, void* d_ws, size_t ws_size,
                              hipStream_t stream) {
    const float* x     = (const float*)d_in[0];
    const float* enc_W = (const float*)d_in[1];
    const float* enc_b = (const float*)d_in[2];
    const float* in_W  = (const float*)d_in[3];
    const float* in_b  = (const float*)d_in[4];
    const float* W_ih  = (const float*)d_in[5];
    const float* W_hh  = (const float*)d_in[6];
    const float* b_ih  = (const float*)d_in[7];
    const float* b_hh  = (const float*)d_in[8];
    const float* out_W = (const float*)d_in[9];
    const float* out_b = (const float*)d_in[10];
    const float* emb   = (const float*)d_in[11];
    const float* sos   = (const float*)d_in[12];

    float* seq    = (float*)d_out;
    float* logits = (float*)d_out + BATCH * SLEN;

    char* p = (char*)d_ws;
    ushort* Wb    = (ushort*)p;  p += (size_t)VOCAB * HSZ * 2;
    float* Wcat2  = (float*)p;   p += (size_t)2048 * 576 * 4;
    float* bcat2  = (float*)p;   p += 2048 * 4;
    float* hA     = (float*)p;   p += (size_t)BATCH * HSZ * 4;
    float* hB     = (float*)p;   p += (size_t)BATCH * HSZ * 4;
    ushort* hbf   = (ushort*)p;  p += (size_t)BATCH * HSZ * 2;
    float* ebuf   = (float*)p;   p += (size_t)BATCH * EMB * 4;
    float* feat   = (float*)p;   p += (size_t)BATCH * DFEAT * 4;
    float* tmaxv  = (float*)p;   p += (size_t)BATCH * 512 * 4;
    int*   flags  = (int*)p;     p += (size_t)BATCH * 4;

    // prologue: weights prep (+flag reset) + encoder -> input_layer -> h0
    prep_kernel<<<1024, 256, 0, stream>>>(out_W, Wb, W_ih, W_hh, b_ih, b_hh,
                                          Wcat2, bcat2, flags);
    gemm_atb<64, 64, 32, 4, 4><<<dim3(DFEAT / 64, BATCH / 64), 256, 0, stream>>>(
        x, enc_W, enc_b, feat, DFEAT, BATCH, DFEAT, DIN);
    gemm_atb<64, 64, 32, 4, 4><<<dim3(HSZ / 64, BATCH / 64), 256, 0, stream>>>(
        feat, in_W, in_b, hA, HSZ, BATCH, HSZ, DFEAT);

    float* hc = hA;
    float* hn = hB;
    for (int t = 0; t < SLEN; ++t) {
        float* lbase = logits + (long long)t * VOCAB;
        if (t == 0) {
            ag_kernel<true><<<576, 256, 0, stream>>>(
                hc, hn, Wcat2, bcat2, ebuf, sos, hbf,
                tmaxv, logits, out_W, out_b, emb, seq, flags, 0, 0);
        } else {
            ag_kernel<false><<<576, 256, 0, stream>>>(
                hc, hn, Wcat2, bcat2, ebuf, sos, hbf,
                tmaxv, logits + (long long)(t - 1) * VOCAB,
                out_W, out_b, emb, seq, flags, t, t - 1);
        }
        logits_bm128_kernel<<<1000, 256, 0, stream>>>(hbf, Wb, out_b, lbase, tmaxv);
        float* tmp = hc; hc = hn; hn = tmp;
    }
    // final argmax for t = 15 (h final state is in hc after last swap)
    argmax_kernel<<<BATCH, 256, 0, stream>>>(
        tmaxv, logits + (long long)(SLEN - 1) * VOCAB, hc, out_W, out_b, emb,
        seq, ebuf, SLEN - 1);
}

// Round 12
// 1657.079 us; speedup vs baseline: 3.5937x; 3.5937x over previous
//
#include <hip/hip_runtime.h>
#include <math.h>

#define BATCH 256
#define DIN 512
#define DFEAT 512
#define HSZ 512
#define VOCAB 32000
#define EMB 64
#define SLEN 16
#define NTILE 500          // VOCAB / 64 col-tiles
#define MARGIN 0.0625f

typedef __attribute__((ext_vector_type(8))) short bf16x8;
typedef __attribute__((ext_vector_type(4))) float f32x4;

__device__ inline unsigned bf16_rne(float x) {
    union { float f; unsigned u; } u; u.f = x;
    unsigned r = u.u + 0x7fff + ((u.u >> 16) & 1);
    return r >> 16;
}

// ---------- fp32 SMEM GEMM (prologue): C = A @ W^T (+bias) ----------
template<int BM, int BN, int BK, int TM, int TN>
__global__ __launch_bounds__(256) void gemm_atb(
    const float* __restrict__ A,
    const float* __restrict__ W,
    const float* __restrict__ bias,
    float* __restrict__ C, long long ldc,
    int M, int N, int K)
{
    __shared__ float As[BK][BM + 4];
    __shared__ float Bs[BK][BN + 4];
    constexpr int THREADS = (BM / TM) * (BN / TN);
    const int tid = threadIdx.x;
    const int tx = tid % (BN / TN);
    const int ty = tid / (BN / TN);
    const int row0 = blockIdx.y * BM;
    const int col0 = blockIdx.x * BN;
    float acc[TM][TN] = {};
    for (int k0 = 0; k0 < K; k0 += BK) {
        for (int i = tid; i < BM * BK; i += THREADS) {
            int m = i / BK, k = i % BK;
            As[k][m] = A[(long long)(row0 + m) * K + k0 + k];
        }
        for (int i = tid; i < BN * BK; i += THREADS) {
            int n = i / BK, k = i % BK;
            Bs[k][n] = W[(long long)(col0 + n) * K + k0 + k];
        }
        __syncthreads();
        #pragma unroll
        for (int kk = 0; kk < BK; ++kk) {
            float a[TM], b[TN];
            #pragma unroll
            for (int i = 0; i < TM; ++i) a[i] = As[kk][ty * TM + i];
            #pragma unroll
            for (int j = 0; j < TN; ++j) b[j] = Bs[kk][tx * TN + j];
            #pragma unroll
            for (int i = 0; i < TM; ++i)
                #pragma unroll
                for (int j = 0; j < TN; ++j)
                    acc[i][j] = fmaf(a[i], b[j], acc[i][j]);
        }
        __syncthreads();
    }
    #pragma unroll
    for (int i = 0; i < TM; ++i) {
        long long m = row0 + ty * TM + i;
        float* crow = C + m * ldc;
        #pragma unroll
        for (int j = 0; j < TN; ++j) {
            int n = col0 + tx * TN + j;
            float v = acc[i][j];
            if (bias) v += bias[n];
            crow[n] = v;
        }
    }
}

// ---------- fused prologue: Wb cast, Wcat2/bcat2 build, done-counter reset ----------
__global__ void prep_kernel(const float* __restrict__ out_W, ushort* __restrict__ Wb,
                            const float* __restrict__ W_ih, const float* __restrict__ W_hh,
                            const float* __restrict__ b_ih, const float* __restrict__ b_hh,
                            float* __restrict__ Wcat2, float* __restrict__ bcat2,
                            int* __restrict__ done)
{
    const int stride = gridDim.x * 256;
    const int t0 = blockIdx.x * 256 + threadIdx.x;
    for (int i = t0; i < VOCAB * HSZ / 4; i += stride) {
        const float4 v = ((const float4*)out_W)[i];
        ushort4 o;
        o.x = (ushort)bf16_rne(v.x); o.y = (ushort)bf16_rne(v.y);
        o.z = (ushort)bf16_rne(v.z); o.w = (ushort)bf16_rne(v.w);
        ((ushort4*)Wb)[i] = o;
    }
    for (long long i = t0; i < 2048LL * 576; i += stride) {
        int g = (int)(i / 576), k = (int)(i % 576);
        int j = g >> 2, comp = g & 3;
        float v;
        if (comp == 0)      v = (k < 64) ? W_ih[j * 64 + k]          : W_hh[(long long)j * 512 + k - 64];
        else if (comp == 1) v = (k < 64) ? W_ih[(512 + j) * 64 + k]  : W_hh[(long long)(512 + j) * 512 + k - 64];
        else if (comp == 2) v = (k < 64) ? W_ih[(1024 + j) * 64 + k] : 0.f;
        else                v = (k < 64) ? 0.f                        : W_hh[(long long)(1024 + j) * 512 + k - 64];
        Wcat2[i] = v;
    }
    for (int i = t0; i < 2048; i += stride) {
        int j = i >> 2, comp = i & 3;
        float bv = (comp == 0) ? b_ih[j] + b_hh[j]
                 : (comp == 1) ? b_ih[512 + j] + b_hh[512 + j]
                 : (comp == 2) ? b_ih[1024 + j] : b_hh[1024 + j];
        bcat2[i] = bv;
    }
    if (t0 == 0) *done = 0;   // replay-safe counter reset
}

// ---------- AG: producer-consumer {argmax(t-1) on 64 blocks} + {G on 512 blocks} ----------
// Fixed protocol: producers RELEASE fetch_add on a single counter after sc1 ebuf stores;
// consumers poll the counter with RELAXED agent loads (no cache maintenance), 1 lane/block.
template<bool FIRST>
__global__ __launch_bounds__(256) void ag_kernel(
    const float* __restrict__ hprev, float* __restrict__ hnew,
    const float* __restrict__ Wcat2, const float* __restrict__ bcat2,
    float* __restrict__ ebuf, const float* __restrict__ sos,
    ushort* __restrict__ hbf,
    const float* __restrict__ tmaxv, const float* __restrict__ lprev,
    const float* __restrict__ out_W, const float* __restrict__ out_b,
    const float* __restrict__ emb, float* __restrict__ seq,
    int* __restrict__ done, int wait_target, int tprev)
{
    const int tid = threadIdx.x;
    const int lane = tid & 63, wave = tid >> 6;

    if (blockIdx.x < 64) {
        // ===== producer: argmax for rows blk*4 .. blk*4+3 (one wave per row) =====
        if (FIRST) return;
        __shared__ int s_qt[4][32];
        __shared__ int s_cc[4][32];
        __shared__ int s_qn[4];
        __shared__ int s_cn[4];
        if (tid < 4) { s_qn[tid] = 0; s_cn[tid] = 0; }
        __syncthreads();
        const int r = blockIdx.x * 4 + wave;
        const float* trow = tmaxv + (long long)r * 512;
        float tv[8];
        float m = -INFINITY;
        #pragma unroll
        for (int s = 0; s < 8; ++s) {
            int i = lane + (s << 6);
            tv[s] = (i < NTILE) ? trow[i] : -INFINITY;
            m = fmaxf(m, tv[s]);
        }
        #pragma unroll
        for (int d = 32; d; d >>= 1) m = fmaxf(m, __shfl_xor(m, d, 64));
        const float thr = m - MARGIN;
        #pragma unroll
        for (int s = 0; s < 8; ++s) {
            int i = lane + (s << 6);
            if (i < NTILE && tv[s] >= thr) {
                int sl = atomicAdd(&s_qn[wave], 1);
                if (sl < 32) s_qt[wave][sl] = i;
            }
        }
        int nq = min(s_qn[wave], 32);
        const float* lrow = lprev + (long long)r * (SLEN * (long long)VOCAB);
        for (int q = 0; q < nq; ++q) {
            float v = lrow[s_qt[wave][q] * 64 + lane];
            if (v >= thr) {
                int sl = atomicAdd(&s_cn[wave], 1);
                if (sl < 32) s_cc[wave][sl] = s_qt[wave][q] * 64 + lane;
            }
        }
        int nc = min(s_cn[wave], 32);
        const float* hrow = hprev + (long long)r * 512;
        float bv = -INFINITY; int bsym = 0x7fffffff;
        for (int ci = 0; ci < nc; ++ci) {
            int cc = s_cc[wave][ci];
            const float* wrow = out_W + (long long)cc * 512;
            float s = 0.f;
            for (int k = lane; k < 512; k += 64) s = fmaf(hrow[k], wrow[k], s);
            #pragma unroll
            for (int off = 32; off; off >>= 1) s += __shfl_down(s, off, 64);
            if (lane == 0) {
                float x = s + out_b[cc];
                if (x > bv || (x == bv && cc < bsym)) { bv = x; bsym = cc; }
            }
        }
        int sym = __shfl(bsym, 0, 64);
        if (sym < 0 || sym >= VOCAB) sym = 0;   // crash-proofing
        if (lane == 0) seq[r * SLEN + tprev] = (float)sym;
        __hip_atomic_store(&ebuf[(long long)r * EMB + lane],
                           emb[(long long)sym * EMB + lane],
                           __ATOMIC_RELAXED, __HIP_MEMORY_SCOPE_AGENT);
        __syncthreads();          // all 4 rows' ebuf stores issued
        if (tid == 0)
            __hip_atomic_fetch_add(done, 1, __ATOMIC_RELEASE, __HIP_MEMORY_SCOPE_AGENT);
        return;
    }

    // ===== consumer: G tile (identical math to validated round-10 kernel) =====
    __shared__ __align__(16) char smem[22528];
    const int blk = blockIdx.x - 64;
    const int ty = blk >> 5;            // 16-row batch group
    const int tx = blk & 31;            // col group (16 j x 4 comps)
    float* As = (float*)smem;                    // [64][18]
    float* Bs = (float*)(smem + 4608);           // [64][68]
    const int tyt = tid >> 4;
    const int txt = tid & 15;

    if (!FIRST) {
        if (tid == 0) {
            // RELAXED poll: plain coherent (sc1) loads, no cache invalidation
            while (__hip_atomic_load(done, __ATOMIC_RELAXED, __HIP_MEMORY_SCOPE_AGENT) < wait_target)
                __builtin_amdgcn_s_sleep(4);
        }
        __syncthreads();
    }

    float acc[4] = {};
    for (int k0 = 0; k0 < 576; k0 += 64) {
        for (int i = tid; i < 16 * 64; i += 256) {
            int m = i >> 6, k = i & 63;
            int kc = k0 + k;
            float v;
            if (kc < 64) {
                if (FIRST) v = sos[kc];
                else v = __hip_atomic_load(&ebuf[(long long)(ty * 16 + m) * EMB + kc],
                                           __ATOMIC_RELAXED, __HIP_MEMORY_SCOPE_AGENT);
            } else {
                v = hprev[(long long)(ty * 16 + m) * 512 + kc - 64];
            }
            As[k * 18 + m] = v;
        }
        for (int i = tid; i < 64 * 64; i += 256) {
            int n = i >> 6, k = i & 63;
            Bs[k * 68 + n] = Wcat2[(long long)(tx * 64 + n) * 576 + k0 + k];
        }
        __syncthreads();
        #pragma unroll 8
        for (int kk = 0; kk < 64; ++kk) {
            const float a = As[kk * 18 + tyt];
            const float4 b = *(const float4*)&Bs[kk * 68 + txt * 4];
            acc[0] = fmaf(a, b.x, acc[0]);
            acc[1] = fmaf(a, b.y, acc[1]);
            acc[2] = fmaf(a, b.z, acc[2]);
            acc[3] = fmaf(a, b.w, acc[3]);
        }
        __syncthreads();
    }
    float* gt = (float*)smem;            // [16][64] reuse
    #pragma unroll
    for (int j = 0; j < 4; ++j)
        gt[tyt * 64 + txt * 4 + j] = acc[j];
    __syncthreads();
    {
        int row = tid >> 4, jl = tid & 15;
        int jg = tx * 16 + jl;
        float gr  = gt[row * 64 + jl * 4 + 0] + bcat2[jg * 4 + 0];
        float gz  = gt[row * 64 + jl * 4 + 1] + bcat2[jg * 4 + 1];
        float gni = gt[row * 64 + jl * 4 + 2] + bcat2[jg * 4 + 2];
        float gnh = gt[row * 64 + jl * 4 + 3] + bcat2[jg * 4 + 3];
        float r = 1.0f / (1.0f + expf(-gr));
        float z = 1.0f / (1.0f + expf(-gz));
        float n = tanhf(gni + r * gnh);
        long long bglob = ty * 16 + row;
        float hold = hprev[bglob * 512 + jg];
        float h = (1.0f - z) * n + z * hold;
        hnew[bglob * 512 + jg] = h;
        hbf[bglob * 512 + jg] = (ushort)bf16_rne(h);
    }
}

// ---------- L: logits MFMA, BM=128 x BN=64, 1000 blocks, XCD-swizzled (round-10) ----------
__global__ __launch_bounds__(256) void logits_bm128_kernel(
    const ushort* __restrict__ hbf,
    const ushort* __restrict__ Wb,
    const float* __restrict__ out_b,
    float* __restrict__ lbase, float* __restrict__ tmaxv)
{
    __shared__ __align__(16) char As[16384];
    __shared__ __align__(16) char Bs[8192];
    __shared__ float s_mv[128];
    const int tid = threadIdx.x;
    const int lane = tid & 63;
    const int wave = tid >> 6;
    const int bid = blockIdx.x;
    const int job = (bid & 7) * 125 + (bid >> 3);
    const int jx = job >> 1;
    const int jy = job & 1;
    const int row0 = jy * 128;
    const int col0 = jx * 64;

    f32x4 acc[2][4] = {};
    const int srow = tid >> 3;
    const int sch = tid & 7;

    for (int k0 = 0; k0 < 512; k0 += 64) {
        #pragma unroll
        for (int ra = 0; ra < 4; ++ra) {
            int row = ra * 32 + srow;
            const char* g = (const char*)(hbf + (long long)(row0 + row) * 512 + k0) + ((sch ^ (row & 7)) * 16);
            __builtin_amdgcn_global_load_lds(
                (const __attribute__((address_space(1))) void*)g,
                (__attribute__((address_space(3))) void*)(As + row * 128 + sch * 16), 16, 0, 0);
        }
        #pragma unroll
        for (int rb = 0; rb < 2; ++rb) {
            int row = rb * 32 + srow;
            const char* g = (const char*)(Wb + (long long)(col0 + row) * 512 + k0) + ((sch ^ (row & 7)) * 16);
            __builtin_amdgcn_global_load_lds(
                (const __attribute__((address_space(1))) void*)g,
                (__attribute__((address_space(3))) void*)(Bs + row * 128 + sch * 16), 16, 0, 0);
        }
        __syncthreads();
        #pragma unroll
        for (int k32 = 0; k32 < 64; k32 += 32) {
            bf16x8 af[2], bfr[4];
            #pragma unroll
            for (int f = 0; f < 2; ++f) {
                int rA = wave * 32 + f * 16 + (lane & 15);
                int byteA = (rA * 128 + (k32 + ((lane >> 4) << 3)) * 2) ^ ((rA & 7) << 4);
                af[f] = *(const bf16x8*)&As[byteA];
            }
            #pragma unroll
            for (int j = 0; j < 4; ++j) {
                int rB = j * 16 + (lane & 15);
                int byteB = (rB * 128 + (k32 + ((lane >> 4) << 3)) * 2) ^ ((rB & 7) << 4);
                bfr[j] = *(const bf16x8*)&Bs[byteB];
            }
            #pragma unroll
            for (int f = 0; f < 2; ++f)
                #pragma unroll
                for (int j = 0; j < 4; ++j)
                    acc[f][j] = __builtin_amdgcn_mfma_f32_16x16x32_bf16(af[f], bfr[j], acc[f][j], 0, 0, 0);
        }
        __syncthreads();
    }

    #pragma unroll
    for (int f = 0; f < 2; ++f) {
        #pragma unroll
        for (int q = 0; q < 4; ++q) {
            int r_local = wave * 32 + f * 16 + ((lane >> 4) << 2) + q;
            float* crow = lbase + (long long)(row0 + r_local) * (SLEN * (long long)VOCAB);
            float mv = -INFINITY;
            #pragma unroll
            for (int j = 0; j < 4; ++j) {
                int c = col0 + j * 16 + (lane & 15);
                float v = acc[f][j][q] + out_b[c];
                __builtin_nontemporal_store(v, &crow[c]);
                mv = fmaxf(mv, v);
            }
            #pragma unroll
            for (int m = 1; m < 16; m <<= 1) mv = fmaxf(mv, __shfl_xor(mv, m, 64));
            if ((lane & 15) == 0) s_mv[r_local] = mv;
        }
    }
    __syncthreads();
    if (tid < 128)
        tmaxv[(long long)(row0 + tid) * 512 + jx] = s_mv[tid];
}

// ---------- final argmax (round-10 validated) ----------
__global__ __launch_bounds__(256) void argmax_kernel(
    const float* __restrict__ tmaxv, const float* __restrict__ lbase,
    const float* __restrict__ h, const float* __restrict__ out_W,
    const float* __restrict__ out_b, const float* __restrict__ emb,
    float* __restrict__ seq, float* __restrict__ ebuf, int t)
{
    __shared__ float s_red[256];
    __shared__ int s_qt[64];
    __shared__ int s_cand[64];
    __shared__ float s_rv[64];
    __shared__ int s_cnt2[2];
    __shared__ int s_sym;
    const int b = blockIdx.x;
    const int tid = threadIdx.x;
    const int lane = tid & 63, wave = tid >> 6;
    const float* row = lbase + (long long)b * (SLEN * (long long)VOCAB);

    float v0 = tmaxv[(long long)b * 512 + tid];
    float v1 = (tid + 256 < NTILE) ? tmaxv[(long long)b * 512 + 256 + tid] : -INFINITY;
    s_red[tid] = fmaxf(v0, v1); __syncthreads();
    for (int s = 128; s > 0; s >>= 1) {
        if (tid < s) s_red[tid] = fmaxf(s_red[tid], s_red[tid + s]);
        __syncthreads();
    }
    float M = s_red[0];
    if (tid == 0) { s_cnt2[0] = 0; s_cnt2[1] = 0; }
    __syncthreads();
    if (v0 >= M - MARGIN) {
        int s = atomicAdd(&s_cnt2[0], 1);
        if (s < 64) s_qt[s] = tid;
    }
    if (v1 >= M - MARGIN) {
        int s = atomicAdd(&s_cnt2[0], 1);
        if (s < 64) s_qt[s] = tid + 256;
    }
    __syncthreads();
    int nq = min(s_cnt2[0], 64);
    for (int idx = tid; idx < nq * 64; idx += 256) {
        int c = s_qt[idx >> 6] * 64 + (idx & 63);
        if (row[c] >= M - MARGIN) {
            int s = atomicAdd(&s_cnt2[1], 1);
            if (s < 64) s_cand[s] = c;
        }
    }
    __syncthreads();
    int nc = min(s_cnt2[1], 64);
    const float* hrow = h + (long long)b * 512;
    for (int ci = wave; ci < nc; ci += 4) {
        int vv = s_cand[ci];
        const float* wrow = out_W + (long long)vv * 512;
        float s = 0.f;
        for (int k = lane; k < 512; k += 64) s = fmaf(hrow[k], wrow[k], s);
        for (int off = 32; off > 0; off >>= 1) s += __shfl_down(s, off, 64);
        if (lane == 0) s_rv[ci] = s + out_b[vv];
    }
    __syncthreads();
    if (tid == 0) {
        float bv = -INFINITY; int sym = 0x7fffffff;
        for (int ci = 0; ci < nc; ++ci) {
            float xx = s_rv[ci]; int c = s_cand[ci];
            if (xx > bv || (xx == bv && c < sym)) { bv = xx; sym = c; }
        }
        if (sym < 0 || sym >= VOCAB) sym = 0;
        seq[b * SLEN + t] = (float)sym;
        s_sym = sym;
    }
    __syncthreads();
    if (tid < EMB) ebuf[(long long)b * EMB + tid] = emb[(long long)s_sym * EMB + tid];
}

extern "C" void kernel_launch(void* const* d_in, const int* in_sizes, int n_in,
                              void* d_out, int out_size, void* d_ws, size_t ws_size,
                              hipStream_t stream) {
    const float* x     = (const float*)d_in[0];
    const float* enc_W = (const float*)d_in[1];
    const float* enc_b = (const float*)d_in[2];
    const float* in_W  = (const float*)d_in[3];
    const float* in_b  = (const float*)d_in[4];
    const float* W_ih  = (const float*)d_in[5];
    const float* W_hh  = (const float*)d_in[6];
    const float* b_ih  = (const float*)d_in[7];
    const float* b_hh  = (const float*)d_in[8];
    const float* out_W = (const float*)d_in[9];
    const float* out_b = (const float*)d_in[10];
    const float* emb   = (const float*)d_in[11];
    const float* sos   = (const float*)d_in[12];

    float* seq    = (float*)d_out;
    float* logits = (float*)d_out + BATCH * SLEN;

    char* p = (char*)d_ws;
    ushort* Wb    = (ushort*)p;  p += (size_t)VOCAB * HSZ * 2;
    float* Wcat2  = (float*)p;   p += (size_t)2048 * 576 * 4;
    float* bcat2  = (float*)p;   p += 2048 * 4;
    float* hA     = (float*)p;   p += (size_t)BATCH * HSZ * 4;
    float* hB     = (float*)p;   p += (size_t)BATCH * HSZ * 4;
    ushort* hbf   = (ushort*)p;  p += (size_t)BATCH * HSZ * 2;
    float* ebuf   = (float*)p;   p += (size_t)BATCH * EMB * 4;
    float* feat   = (float*)p;   p += (size_t)BATCH * DFEAT * 4;
    float* tmaxv  = (float*)p;   p += (size_t)BATCH * 512 * 4;
    int*   done   = (int*)p;     p += 64;

    // prologue: weights prep (+counter reset) + encoder -> input_layer -> h0
    prep_kernel<<<1024, 256, 0, stream>>>(out_W, Wb, W_ih, W_hh, b_ih, b_hh,
                                          Wcat2, bcat2, done);
    gemm_atb<64, 64, 32, 4, 4><<<dim3(DFEAT / 64, BATCH / 64), 256, 0, stream>>>(
        x, enc_W, enc_b, feat, DFEAT, BATCH, DFEAT, DIN);
    gemm_atb<64, 64, 32, 4, 4><<<dim3(HSZ / 64, BATCH / 64), 256, 0, stream>>>(
        feat, in_W, in_b, hA, HSZ, BATCH, HSZ, DFEAT);

    float* hc = hA;
    float* hn = hB;
    for (int t = 0; t < SLEN; ++t) {
        float* lbase = logits + (long long)t * VOCAB;
        if (t == 0) {
            ag_kernel<true><<<576, 256, 0, stream>>>(
                hc, hn, Wcat2, bcat2, ebuf, sos, hbf,
                tmaxv, logits, out_W, out_b, emb, seq, done, 0, 0);
        } else {
            ag_kernel<false><<<576, 256, 0, stream>>>(
                hc, hn, Wcat2, bcat2, ebuf, sos, hbf,
                tmaxv, logits + (long long)(t - 1) * VOCAB,
                out_W, out_b, emb, seq, done, 64 * t, t - 1);
        }
        logits_bm128_kernel<<<1000, 256, 0, stream>>>(hbf, Wb, out_b, lbase, tmaxv);
        float* tmp = hc; hc = hn; hn = tmp;
    }
    // final argmax for t = 15 (h final state is in hc after last swap)
    argmax_kernel<<<BATCH, 256, 0, stream>>>(
        tmaxv, logits + (long long)(SLEN - 1) * VOCAB, hc, out_W, out_b, emb,
        seq, ebuf, SLEN - 1);
}

// Round 13
// 1268.797 us; speedup vs baseline: 4.6934x; 1.3060x over previous
//
#include <hip/hip_runtime.h>
#include <math.h>

#define BATCH 256
#define DIN 512
#define DFEAT 512
#define HSZ 512
#define VOCAB 32000
#define EMB 64
#define SLEN 16
#define NTILE 250          // VOCAB / 128 col-tiles
#define MARGIN 0.0625f

typedef __attribute__((ext_vector_type(8))) short bf16x8;
typedef __attribute__((ext_vector_type(4))) float f32x4;

__device__ inline unsigned bf16_rne(float x) {
    union { float f; unsigned u; } u; u.f = x;
    unsigned r = u.u + 0x7fff + ((u.u >> 16) & 1);
    return r >> 16;
}

// ---------- fp32 SMEM GEMM (prologue): C = A @ W^T (+bias) ----------
template<int BM, int BN, int BK, int TM, int TN>
__global__ __launch_bounds__(256) void gemm_atb(
    const float* __restrict__ A,
    const float* __restrict__ W,
    const float* __restrict__ bias,
    float* __restrict__ C, long long ldc,
    int M, int N, int K)
{
    __shared__ float As[BK][BM + 4];
    __shared__ float Bs[BK][BN + 4];
    constexpr int THREADS = (BM / TM) * (BN / TN);
    const int tid = threadIdx.x;
    const int tx = tid % (BN / TN);
    const int ty = tid / (BN / TN);
    const int row0 = blockIdx.y * BM;
    const int col0 = blockIdx.x * BN;
    float acc[TM][TN] = {};
    for (int k0 = 0; k0 < K; k0 += BK) {
        for (int i = tid; i < BM * BK; i += THREADS) {
            int m = i / BK, k = i % BK;
            As[k][m] = A[(long long)(row0 + m) * K + k0 + k];
        }
        for (int i = tid; i < BN * BK; i += THREADS) {
            int n = i / BK, k = i % BK;
            Bs[k][n] = W[(long long)(col0 + n) * K + k0 + k];
        }
        __syncthreads();
        #pragma unroll
        for (int kk = 0; kk < BK; ++kk) {
            float a[TM], b[TN];
            #pragma unroll
            for (int i = 0; i < TM; ++i) a[i] = As[kk][ty * TM + i];
            #pragma unroll
            for (int j = 0; j < TN; ++j) b[j] = Bs[kk][tx * TN + j];
            #pragma unroll
            for (int i = 0; i < TM; ++i)
                #pragma unroll
                for (int j = 0; j < TN; ++j)
                    acc[i][j] = fmaf(a[i], b[j], acc[i][j]);
        }
        __syncthreads();
    }
    #pragma unroll
    for (int i = 0; i < TM; ++i) {
        long long m = row0 + ty * TM + i;
        float* crow = C + m * ldc;
        #pragma unroll
        for (int j = 0; j < TN; ++j) {
            int n = col0 + tx * TN + j;
            float v = acc[i][j];
            if (bias) v += bias[n];
            crow[n] = v;
        }
    }
}

// ---------- fused prologue: Wb cast, Wcat2/bcat2 build ----------
__global__ void prep_kernel(const float* __restrict__ out_W, ushort* __restrict__ Wb,
                            const float* __restrict__ W_ih, const float* __restrict__ W_hh,
                            const float* __restrict__ b_ih, const float* __restrict__ b_hh,
                            float* __restrict__ Wcat2, float* __restrict__ bcat2)
{
    const int stride = gridDim.x * 256;
    const int t0 = blockIdx.x * 256 + threadIdx.x;
    for (int i = t0; i < VOCAB * HSZ / 4; i += stride) {
        const float4 v = ((const float4*)out_W)[i];
        ushort4 o;
        o.x = (ushort)bf16_rne(v.x); o.y = (ushort)bf16_rne(v.y);
        o.z = (ushort)bf16_rne(v.z); o.w = (ushort)bf16_rne(v.w);
        ((ushort4*)Wb)[i] = o;
    }
    for (long long i = t0; i < 2048LL * 576; i += stride) {
        int g = (int)(i / 576), k = (int)(i % 576);
        int j = g >> 2, comp = g & 3;
        float v;
        if (comp == 0)      v = (k < 64) ? W_ih[j * 64 + k]          : W_hh[(long long)j * 512 + k - 64];
        else if (comp == 1) v = (k < 64) ? W_ih[(512 + j) * 64 + k]  : W_hh[(long long)(512 + j) * 512 + k - 64];
        else if (comp == 2) v = (k < 64) ? W_ih[(1024 + j) * 64 + k] : 0.f;
        else                v = (k < 64) ? 0.f                        : W_hh[(long long)(1024 + j) * 512 + k - 64];
        Wcat2[i] = v;
    }
    for (int i = t0; i < 2048; i += stride) {
        int j = i >> 2, comp = i & 3;
        float bv = (comp == 0) ? b_ih[j] + b_hh[j]
                 : (comp == 1) ? b_ih[512 + j] + b_hh[512 + j]
                 : (comp == 2) ? b_ih[1024 + j] : b_hh[1024 + j];
        bcat2[i] = bv;
    }
}

// ---------- G: gcat GEMM + GRU gates. 512 blocks (16 rows x 64 interleaved cols) ----------
template<bool FIRST>
__global__ __launch_bounds__(256) void gru_fused_kernel(
    const float* __restrict__ hprev, float* __restrict__ hnew,
    const float* __restrict__ Wcat2, const float* __restrict__ bcat2,
    const float* __restrict__ ebuf, const float* __restrict__ sos,
    ushort* __restrict__ hbf)
{
    __shared__ __align__(16) char smem[22528];
    const int tid = threadIdx.x;
    const int blk = blockIdx.x;
    const int ty = blk >> 5;            // 16-row batch group (0..15)
    const int tx = blk & 31;            // col group (16 j x 4 comps)
    float* As = (float*)smem;                    // [64][18]
    float* Bs = (float*)(smem + 4608);           // [64][68]
    const int tyt = tid >> 4;           // row 0..15
    const int txt = tid & 15;           // 4 cols
    float acc[4] = {};
    for (int k0 = 0; k0 < 576; k0 += 64) {
        for (int i = tid; i < 16 * 64; i += 256) {
            int m = i >> 6, k = i & 63;
            int kc = k0 + k;
            float v;
            if (kc < 64) v = FIRST ? sos[kc] : ebuf[(long long)(ty * 16 + m) * 64 + kc];
            else         v = hprev[(long long)(ty * 16 + m) * 512 + kc - 64];
            As[k * 18 + m] = v;
        }
        for (int i = tid; i < 64 * 64; i += 256) {
            int n = i >> 6, k = i & 63;
            Bs[k * 68 + n] = Wcat2[(long long)(tx * 64 + n) * 576 + k0 + k];
        }
        __syncthreads();
        #pragma unroll 8
        for (int kk = 0; kk < 64; ++kk) {
            const float a = As[kk * 18 + tyt];
            const float4 b = *(const float4*)&Bs[kk * 68 + txt * 4];
            acc[0] = fmaf(a, b.x, acc[0]);
            acc[1] = fmaf(a, b.y, acc[1]);
            acc[2] = fmaf(a, b.z, acc[2]);
            acc[3] = fmaf(a, b.w, acc[3]);
        }
        __syncthreads();
    }
    float* gt = (float*)smem;            // [16][64] reuse
    #pragma unroll
    for (int j = 0; j < 4; ++j)
        gt[tyt * 64 + txt * 4 + j] = acc[j];
    __syncthreads();
    {
        int row = tid >> 4, jl = tid & 15;     // 256 gate elems: 16 rows x 16 j
        int jg = tx * 16 + jl;
        float gr  = gt[row * 64 + jl * 4 + 0] + bcat2[jg * 4 + 0];
        float gz  = gt[row * 64 + jl * 4 + 1] + bcat2[jg * 4 + 1];
        float gni = gt[row * 64 + jl * 4 + 2] + bcat2[jg * 4 + 2];
        float gnh = gt[row * 64 + jl * 4 + 3] + bcat2[jg * 4 + 3];
        float r = 1.0f / (1.0f + expf(-gr));
        float z = 1.0f / (1.0f + expf(-gz));
        float n = tanhf(gni + r * gnh);
        long long bglob = ty * 16 + row;
        float hold = hprev[bglob * 512 + jg];
        float h = (1.0f - z) * n + z * hold;
        hnew[bglob * 512 + jg] = h;
        hbf[bglob * 512 + jg] = (ushort)bf16_rne(h);
    }
}

// ---------- L: logits MFMA, BM=128 x BN=128, 512 threads (8 waves), 500 blocks ----------
__global__ __launch_bounds__(512) void logits_l512_kernel(
    const ushort* __restrict__ hbf,   // [256][512] bf16
    const ushort* __restrict__ Wb,    // [VOCAB][512] bf16
    const float* __restrict__ out_b,
    float* __restrict__ lbase, float* __restrict__ tmaxv)
{
    __shared__ __align__(16) char As[16384];   // 128 x 64 bf16, XOR-swizzled rows
    __shared__ __align__(16) char Bs[16384];   // 128 x 64 bf16
    __shared__ float s_mv[128][4];
    const int tid = threadIdx.x;
    const int lane = tid & 63;
    const int wave = tid >> 6;        // 8 waves: wr = wave>>2 (row half), wc = wave&3 (col quarter)
    const int wr = wave >> 2, wc = wave & 3;
    // bijective XCD swizzle for 500 blocks over 8 XCDs (m204): q=62, r=4
    const int orig = blockIdx.x;
    const int xcd = orig & 7, idx = orig >> 3;
    const int job = (xcd < 4 ? xcd * 63 : 4 * 63 + (xcd - 4) * 62) + idx;
    const int jx = job >> 1;          // 0..249
    const int jy = job & 1;
    const int row0 = jy * 128;
    const int col0 = jx * 128;

    f32x4 acc[4][2] = {};
    const int srow = tid >> 3;        // 0..63
    const int sch = tid & 7;

    for (int k0 = 0; k0 < 512; k0 += 64) {
        #pragma unroll
        for (int ra = 0; ra < 2; ++ra) {
            int row = ra * 64 + srow;
            const char* g = (const char*)(hbf + (long long)(row0 + row) * 512 + k0) + ((sch ^ (row & 7)) * 16);
            __builtin_amdgcn_global_load_lds(
                (const __attribute__((address_space(1))) void*)g,
                (__attribute__((address_space(3))) void*)(As + row * 128 + sch * 16), 16, 0, 0);
        }
        #pragma unroll
        for (int rb = 0; rb < 2; ++rb) {
            int row = rb * 64 + srow;
            const char* g = (const char*)(Wb + (long long)(col0 + row) * 512 + k0) + ((sch ^ (row & 7)) * 16);
            __builtin_amdgcn_global_load_lds(
                (const __attribute__((address_space(1))) void*)g,
                (__attribute__((address_space(3))) void*)(Bs + row * 128 + sch * 16), 16, 0, 0);
        }
        __syncthreads();
        #pragma unroll
        for (int k32 = 0; k32 < 64; k32 += 32) {
            bf16x8 af[4], bfr[2];
            #pragma unroll
            for (int f = 0; f < 4; ++f) {
                int rA = wr * 64 + f * 16 + (lane & 15);
                int byteA = (rA * 128 + (k32 + ((lane >> 4) << 3)) * 2) ^ ((rA & 7) << 4);
                af[f] = *(const bf16x8*)&As[byteA];
            }
            #pragma unroll
            for (int j = 0; j < 2; ++j) {
                int rB = wc * 32 + j * 16 + (lane & 15);
                int byteB = (rB * 128 + (k32 + ((lane >> 4) << 3)) * 2) ^ ((rB & 7) << 4);
                bfr[j] = *(const bf16x8*)&Bs[byteB];
            }
            #pragma unroll
            for (int f = 0; f < 4; ++f)
                #pragma unroll
                for (int j = 0; j < 2; ++j)
                    acc[f][j] = __builtin_amdgcn_mfma_f32_16x16x32_bf16(af[f], bfr[j], acc[f][j], 0, 0, 0);
        }
        __syncthreads();
    }

    // epilogue: bias + nontemporal store + per-row max over this wave's 32 cols
    #pragma unroll
    for (int f = 0; f < 4; ++f) {
        #pragma unroll
        for (int q = 0; q < 4; ++q) {
            int r_local = wr * 64 + f * 16 + ((lane >> 4) << 2) + q;
            float* crow = lbase + (long long)(row0 + r_local) * (SLEN * (long long)VOCAB);
            float mv = -INFINITY;
            #pragma unroll
            for (int j = 0; j < 2; ++j) {
                int c = col0 + wc * 32 + j * 16 + (lane & 15);
                float v = acc[f][j][q] + out_b[c];
                __builtin_nontemporal_store(v, &crow[c]);
                mv = fmaxf(mv, v);
            }
            #pragma unroll
            for (int m = 1; m < 16; m <<= 1) mv = fmaxf(mv, __shfl_xor(mv, m, 64));
            if ((lane & 15) == 0) s_mv[r_local][wc] = mv;
        }
    }
    __syncthreads();
    if (tid < 128) {
        float m0 = fmaxf(s_mv[tid][0], s_mv[tid][1]);
        float m1 = fmaxf(s_mv[tid][2], s_mv[tid][3]);
        tmaxv[(long long)(row0 + tid) * 512 + jx] = fmaxf(m0, m1);
    }
}

// ---------- A: per-row argmax via 250 tile-maxes (128-wide) + exact fp32 refine ----------
__global__ __launch_bounds__(256) void argmax_kernel(
    const float* __restrict__ tmaxv, const float* __restrict__ lbase,
    const float* __restrict__ h, const float* __restrict__ out_W,
    const float* __restrict__ out_b, const float* __restrict__ emb,
    float* __restrict__ seq, float* __restrict__ ebuf, int t)
{
    __shared__ float s_red[256];
    __shared__ int s_qt[64];
    __shared__ int s_cand[64];
    __shared__ float s_rv[64];
    __shared__ int s_cnt2[2];
    __shared__ int s_sym;
    const int b = blockIdx.x;
    const int tid = threadIdx.x;
    const int lane = tid & 63, wave = tid >> 6;
    const float* row = lbase + (long long)b * (SLEN * (long long)VOCAB);

    float v0 = (tid < NTILE) ? tmaxv[(long long)b * 512 + tid] : -INFINITY;
    s_red[tid] = v0; __syncthreads();
    for (int s = 128; s > 0; s >>= 1) {
        if (tid < s) s_red[tid] = fmaxf(s_red[tid], s_red[tid + s]);
        __syncthreads();
    }
    float M = s_red[0];
    if (tid == 0) { s_cnt2[0] = 0; s_cnt2[1] = 0; }
    __syncthreads();
    if (v0 >= M - MARGIN) {
        int s = atomicAdd(&s_cnt2[0], 1);
        if (s < 64) s_qt[s] = tid;
    }
    __syncthreads();
    int nq = min(s_cnt2[0], 64);
    for (int idx = tid; idx < nq * 128; idx += 256) {
        int c = s_qt[idx >> 7] * 128 + (idx & 127);
        if (row[c] >= M - MARGIN) {
            int s = atomicAdd(&s_cnt2[1], 1);
            if (s < 64) s_cand[s] = c;
        }
    }
    __syncthreads();
    int nc = min(s_cnt2[1], 64);
    const float* hrow = h + (long long)b * 512;
    for (int ci = wave; ci < nc; ci += 4) {
        int vv = s_cand[ci];
        const float* wrow = out_W + (long long)vv * 512;
        float s = 0.f;
        for (int k = lane; k < 512; k += 64) s = fmaf(hrow[k], wrow[k], s);
        for (int off = 32; off > 0; off >>= 1) s += __shfl_down(s, off, 64);
        if (lane == 0) s_rv[ci] = s + out_b[vv];
    }
    __syncthreads();
    if (tid == 0) {
        float bv = -INFINITY; int sym = 0x7fffffff;
        for (int ci = 0; ci < nc; ++ci) {
            float xx = s_rv[ci]; int c = s_cand[ci];
            if (xx > bv || (xx == bv && c < sym)) { bv = xx; sym = c; }
        }
        if (sym < 0 || sym >= VOCAB) sym = 0;   // crash-proofing
        seq[b * SLEN + t] = (float)sym;
        s_sym = sym;
    }
    __syncthreads();
    if (tid < EMB) ebuf[(long long)b * EMB + tid] = emb[(long long)s_sym * EMB + tid];
}

extern "C" void kernel_launch(void* const* d_in, const int* in_sizes, int n_in,
                              void* d_out, int out_size, void* d_ws, size_t ws_size,
                              hipStream_t stream) {
    const float* x     = (const float*)d_in[0];
    const float* enc_W = (const float*)d_in[1];
    const float* enc_b = (const float*)d_in[2];
    const float* in_W  = (const float*)d_in[3];
    const float* in_b  = (const float*)d_in[4];
    const float* W_ih  = (const float*)d_in[5];
    const float* W_hh  = (const float*)d_in[6];
    const float* b_ih  = (const float*)d_in[7];
    const float* b_hh  = (const float*)d_in[8];
    const float* out_W = (const float*)d_in[9];
    const float* out_b = (const float*)d_in[10];
    const float* emb   = (const float*)d_in[11];
    const float* sos   = (const float*)d_in[12];

    float* seq    = (float*)d_out;
    float* logits = (float*)d_out + BATCH * SLEN;

    char* p = (char*)d_ws;
    ushort* Wb    = (ushort*)p;  p += (size_t)VOCAB * HSZ * 2;
    float* Wcat2  = (float*)p;   p += (size_t)2048 * 576 * 4;
    float* bcat2  = (float*)p;   p += 2048 * 4;
    float* hA     = (float*)p;   p += (size_t)BATCH * HSZ * 4;
    float* hB     = (float*)p;   p += (size_t)BATCH * HSZ * 4;
    ushort* hbf   = (ushort*)p;  p += (size_t)BATCH * HSZ * 2;
    float* ebuf   = (float*)p;   p += (size_t)BATCH * EMB * 4;
    float* feat   = (float*)p;   p += (size_t)BATCH * DFEAT * 4;
    float* tmaxv  = (float*)p;   p += (size_t)BATCH * 512 * 4;

    // prologue: weights prep + encoder -> input_layer -> h0 (into hA)
    prep_kernel<<<1024, 256, 0, stream>>>(out_W, Wb, W_ih, W_hh, b_ih, b_hh, Wcat2, bcat2);
    gemm_atb<64, 64, 32, 4, 4><<<dim3(DFEAT / 64, BATCH / 64), 256, 0, stream>>>(
        x, enc_W, enc_b, feat, DFEAT, BATCH, DFEAT, DIN);
    gemm_atb<64, 64, 32, 4, 4><<<dim3(HSZ / 64, BATCH / 64), 256, 0, stream>>>(
        feat, in_W, in_b, hA, HSZ, BATCH, HSZ, DFEAT);

    float* hc = hA;
    float* hn = hB;
    for (int t = 0; t < SLEN; ++t) {
        float* lbase = logits + (long long)t * VOCAB;
        if (t == 0) {
            gru_fused_kernel<true><<<512, 256, 0, stream>>>(
                hc, hn, Wcat2, bcat2, ebuf, sos, hbf);
        } else {
            gru_fused_kernel<false><<<512, 256, 0, stream>>>(
                hc, hn, Wcat2, bcat2, ebuf, sos, hbf);
        }
        logits_l512_kernel<<<500, 512, 0, stream>>>(hbf, Wb, out_b, lbase, tmaxv);
        argmax_kernel<<<BATCH, 256, 0, stream>>>(
            tmaxv, lbase, hn, out_W, out_b, emb, seq, ebuf, t);
        float* tmp = hc; hc = hn; hn = tmp;
    }
}

// Round 14
// 1150.475 us; speedup vs baseline: 5.1761x; 1.1028x over previous
//
#include <hip/hip_runtime.h>
#include <math.h>

#define BATCH 256
#define DIN 512
#define DFEAT 512
#define HSZ 512
#define VOCAB 32000
#define EMB 64
#define SLEN 16
#define NTILE 500          // VOCAB / 64 col-tiles (for argmax)
#define MARGIN 0.0625f

typedef __attribute__((ext_vector_type(8))) short bf16x8;
typedef __attribute__((ext_vector_type(4))) float f32x4;

__device__ inline unsigned bf16_rne(float x) {
    union { float f; unsigned u; } u; u.f = x;
    unsigned r = u.u + 0x7fff + ((u.u >> 16) & 1);
    return r >> 16;
}

// ---------- fp32 SMEM GEMM (prologue): C = A @ W^T (+bias) ----------
template<int BM, int BN, int BK, int TM, int TN>
__global__ __launch_bounds__(256) void gemm_atb(
    const float* __restrict__ A,
    const float* __restrict__ W,
    const float* __restrict__ bias,
    float* __restrict__ C, long long ldc,
    int M, int N, int K)
{
    __shared__ float As[BK][BM + 4];
    __shared__ float Bs[BK][BN + 4];
    constexpr int THREADS = (BM / TM) * (BN / TN);
    const int tid = threadIdx.x;
    const int tx = tid % (BN / TN);
    const int ty = tid / (BN / TN);
    const int row0 = blockIdx.y * BM;
    const int col0 = blockIdx.x * BN;
    float acc[TM][TN] = {};
    for (int k0 = 0; k0 < K; k0 += BK) {
        for (int i = tid; i < BM * BK; i += THREADS) {
            int m = i / BK, k = i % BK;
            As[k][m] = A[(long long)(row0 + m) * K + k0 + k];
        }
        for (int i = tid; i < BN * BK; i += THREADS) {
            int n = i / BK, k = i % BK;
            Bs[k][n] = W[(long long)(col0 + n) * K + k0 + k];
        }
        __syncthreads();
        #pragma unroll
        for (int kk = 0; kk < BK; ++kk) {
            float a[TM], b[TN];
            #pragma unroll
            for (int i = 0; i < TM; ++i) a[i] = As[kk][ty * TM + i];
            #pragma unroll
            for (int j = 0; j < TN; ++j) b[j] = Bs[kk][tx * TN + j];
            #pragma unroll
            for (int i = 0; i < TM; ++i)
                #pragma unroll
                for (int j = 0; j < TN; ++j)
                    acc[i][j] = fmaf(a[i], b[j], acc[i][j]);
        }
        __syncthreads();
    }
    #pragma unroll
    for (int i = 0; i < TM; ++i) {
        long long m = row0 + ty * TM + i;
        float* crow = C + m * ldc;
        #pragma unroll
        for (int j = 0; j < TN; ++j) {
            int n = col0 + tx * TN + j;
            float v = acc[i][j];
            if (bias) v += bias[n];
            crow[n] = v;
        }
    }
}

// ---------- fused prologue: Wb cast, Wcat2/bcat2 build, done-counter reset ----------
__global__ void prep_kernel(const float* __restrict__ out_W, ushort* __restrict__ Wb,
                            const float* __restrict__ W_ih, const float* __restrict__ W_hh,
                            const float* __restrict__ b_ih, const float* __restrict__ b_hh,
                            float* __restrict__ Wcat2, float* __restrict__ bcat2,
                            int* __restrict__ done)
{
    const int stride = gridDim.x * 256;
    const int t0 = blockIdx.x * 256 + threadIdx.x;
    for (int i = t0; i < VOCAB * HSZ / 4; i += stride) {
        const float4 v = ((const float4*)out_W)[i];
        ushort4 o;
        o.x = (ushort)bf16_rne(v.x); o.y = (ushort)bf16_rne(v.y);
        o.z = (ushort)bf16_rne(v.z); o.w = (ushort)bf16_rne(v.w);
        ((ushort4*)Wb)[i] = o;
    }
    for (long long i = t0; i < 2048LL * 576; i += stride) {
        int g = (int)(i / 576), k = (int)(i % 576);
        int j = g >> 2, comp = g & 3;
        float v;
        if (comp == 0)      v = (k < 64) ? W_ih[j * 64 + k]          : W_hh[(long long)j * 512 + k - 64];
        else if (comp == 1) v = (k < 64) ? W_ih[(512 + j) * 64 + k]  : W_hh[(long long)(512 + j) * 512 + k - 64];
        else if (comp == 2) v = (k < 64) ? W_ih[(1024 + j) * 64 + k] : 0.f;
        else                v = (k < 64) ? 0.f                        : W_hh[(long long)(1024 + j) * 512 + k - 64];
        Wcat2[i] = v;
    }
    for (int i = t0; i < 2048; i += stride) {
        int j = i >> 2, comp = i & 3;
        float bv = (comp == 0) ? b_ih[j] + b_hh[j]
                 : (comp == 1) ? b_ih[512 + j] + b_hh[512 + j]
                 : (comp == 2) ? b_ih[1024 + j] : b_hh[1024 + j];
        bcat2[i] = bv;
    }
    if (t0 == 0) *done = 0;   // replay-safe counter reset
}

// ---------- AG2: fused {argmax(t-1) on blocks 0..255} + {G tile on all 512 blocks} ----------
// Key: G computes the h-part (K=64..575) FIRST; only the final e-part (K=0..63) needs
// ebuf, so the RELAXED poll sits after ~8/9 of G's compute and overlaps A entirely.
template<bool FIRST>
__global__ __launch_bounds__(256) void ag2_kernel(
    const float* __restrict__ hprev, float* __restrict__ hnew,
    const float* __restrict__ Wcat2, const float* __restrict__ bcat2,
    float* __restrict__ ebuf, const float* __restrict__ sos,
    ushort* __restrict__ hbf,
    const float* __restrict__ tmaxv, const float* __restrict__ lprev,
    const float* __restrict__ out_W, const float* __restrict__ out_b,
    const float* __restrict__ emb, float* __restrict__ seq,
    int* __restrict__ done, int wait_target, int tprev)
{
    __shared__ __align__(16) char smem[22528];
    __shared__ float s_red[256];
    __shared__ int s_qt[64];
    __shared__ int s_cand[64];
    __shared__ float s_rv[64];
    __shared__ int s_cnt2[2];
    __shared__ int s_sym;
    const int tid = threadIdx.x;
    const int lane = tid & 63, wave = tid >> 6;
    const int blk = blockIdx.x;

    // ===== A-part: blocks 0..255 each do the full argmax for one batch row =====
    if (!FIRST && blk < BATCH) {
        const int b = blk;
        const float* row = lprev + (long long)b * (SLEN * (long long)VOCAB);
        float v0 = tmaxv[(long long)b * 512 + tid];
        float v1 = (tid + 256 < NTILE) ? tmaxv[(long long)b * 512 + 256 + tid] : -INFINITY;
        s_red[tid] = fmaxf(v0, v1); __syncthreads();
        for (int s = 128; s > 0; s >>= 1) {
            if (tid < s) s_red[tid] = fmaxf(s_red[tid], s_red[tid + s]);
            __syncthreads();
        }
        float M = s_red[0];
        if (tid == 0) { s_cnt2[0] = 0; s_cnt2[1] = 0; }
        __syncthreads();
        if (v0 >= M - MARGIN) {
            int s = atomicAdd(&s_cnt2[0], 1);
            if (s < 64) s_qt[s] = tid;
        }
        if (v1 >= M - MARGIN) {
            int s = atomicAdd(&s_cnt2[0], 1);
            if (s < 64) s_qt[s] = tid + 256;
        }
        __syncthreads();
        int nq = min(s_cnt2[0], 64);
        for (int idx = tid; idx < nq * 64; idx += 256) {
            int c = s_qt[idx >> 6] * 64 + (idx & 63);
            if (row[c] >= M - MARGIN) {
                int s = atomicAdd(&s_cnt2[1], 1);
                if (s < 64) s_cand[s] = c;
            }
        }
        __syncthreads();
        int nc = min(s_cnt2[1], 64);
        const float* hrow = hprev + (long long)b * 512;
        for (int ci = wave; ci < nc; ci += 4) {
            int vv = s_cand[ci];
            const float* wrow = out_W + (long long)vv * 512;
            float s = 0.f;
            for (int k = lane; k < 512; k += 64) s = fmaf(hrow[k], wrow[k], s);
            for (int off = 32; off > 0; off >>= 1) s += __shfl_down(s, off, 64);
            if (lane == 0) s_rv[ci] = s + out_b[vv];
        }
        __syncthreads();
        if (tid == 0) {
            float bv = -INFINITY; int sym = 0x7fffffff;
            for (int ci = 0; ci < nc; ++ci) {
                float xx = s_rv[ci]; int c = s_cand[ci];
                if (xx > bv || (xx == bv && c < sym)) { bv = xx; sym = c; }
            }
            if (sym < 0 || sym >= VOCAB) sym = 0;   // crash-proofing
            seq[b * SLEN + tprev] = (float)sym;
            s_sym = sym;
        }
        __syncthreads();
        if (tid < EMB)
            __hip_atomic_store(&ebuf[(long long)b * EMB + tid],
                               emb[(long long)s_sym * EMB + tid],
                               __ATOMIC_RELAXED, __HIP_MEMORY_SCOPE_AGENT);
        __syncthreads();     // ebuf stores issued by all lanes
        if (tid == 0)
            __hip_atomic_fetch_add(done, 1, __ATOMIC_RELEASE, __HIP_MEMORY_SCOPE_AGENT);
        __syncthreads();
    }

    // ===== G-part (all 512 blocks): h-part of gcat first, e-part last =====
    const int ty = blk >> 5;            // 16-row batch group
    const int tx = blk & 31;            // col group (16 j x 4 comps)
    float* As = (float*)smem;                    // [64][18]
    float* Bs = (float*)(smem + 4608);           // [64][68]
    const int tyt = tid >> 4;
    const int txt = tid & 15;
    float acc[4] = {};

    // h-part: K = 64..575 (8 iterations)
    for (int k0 = 64; k0 < 576; k0 += 64) {
        for (int i = tid; i < 16 * 64; i += 256) {
            int m = i >> 6, k = i & 63;
            As[k * 18 + m] = hprev[(long long)(ty * 16 + m) * 512 + (k0 - 64) + k];
        }
        for (int i = tid; i < 64 * 64; i += 256) {
            int n = i >> 6, k = i & 63;
            Bs[k * 68 + n] = Wcat2[(long long)(tx * 64 + n) * 576 + k0 + k];
        }
        __syncthreads();
        #pragma unroll 8
        for (int kk = 0; kk < 64; ++kk) {
            const float a = As[kk * 18 + tyt];
            const float4 b = *(const float4*)&Bs[kk * 68 + txt * 4];
            acc[0] = fmaf(a, b.x, acc[0]);
            acc[1] = fmaf(a, b.y, acc[1]);
            acc[2] = fmaf(a, b.z, acc[2]);
            acc[3] = fmaf(a, b.w, acc[3]);
        }
        __syncthreads();
    }

    // wait for all 256 A-parts (overlapped with the h-part above), then e-part K=0..63
    if (!FIRST) {
        if (tid == 0) {
            while (__hip_atomic_load(done, __ATOMIC_RELAXED, __HIP_MEMORY_SCOPE_AGENT) < wait_target)
                __builtin_amdgcn_s_sleep(8);
            __hip_atomic_load(done, __ATOMIC_ACQUIRE, __HIP_MEMORY_SCOPE_AGENT);  // one acquire
        }
        __syncthreads();
    }
    {
        for (int i = tid; i < 16 * 64; i += 256) {
            int m = i >> 6, k = i & 63;
            float v;
            if (FIRST) v = sos[k];
            else v = __hip_atomic_load(&ebuf[(long long)(ty * 16 + m) * EMB + k],
                                       __ATOMIC_RELAXED, __HIP_MEMORY_SCOPE_AGENT);
            As[k * 18 + m] = v;
        }
        for (int i = tid; i < 64 * 64; i += 256) {
            int n = i >> 6, k = i & 63;
            Bs[k * 68 + n] = Wcat2[(long long)(tx * 64 + n) * 576 + k];
        }
        __syncthreads();
        #pragma unroll 8
        for (int kk = 0; kk < 64; ++kk) {
            const float a = As[kk * 18 + tyt];
            const float4 b = *(const float4*)&Bs[kk * 68 + txt * 4];
            acc[0] = fmaf(a, b.x, acc[0]);
            acc[1] = fmaf(a, b.y, acc[1]);
            acc[2] = fmaf(a, b.z, acc[2]);
            acc[3] = fmaf(a, b.w, acc[3]);
        }
        __syncthreads();
    }

    float* gt = (float*)smem;            // [16][64] reuse
    #pragma unroll
    for (int j = 0; j < 4; ++j)
        gt[tyt * 64 + txt * 4 + j] = acc[j];
    __syncthreads();
    {
        int row = tid >> 4, jl = tid & 15;
        int jg = tx * 16 + jl;
        float gr  = gt[row * 64 + jl * 4 + 0] + bcat2[jg * 4 + 0];
        float gz  = gt[row * 64 + jl * 4 + 1] + bcat2[jg * 4 + 1];
        float gni = gt[row * 64 + jl * 4 + 2] + bcat2[jg * 4 + 2];
        float gnh = gt[row * 64 + jl * 4 + 3] + bcat2[jg * 4 + 3];
        float r = 1.0f / (1.0f + expf(-gr));
        float z = 1.0f / (1.0f + expf(-gz));
        float n = tanhf(gni + r * gnh);
        long long bglob = ty * 16 + row;
        float hold = hprev[bglob * 512 + jg];
        float h = (1.0f - z) * n + z * hold;
        hnew[bglob * 512 + jg] = h;
        hbf[bglob * 512 + jg] = (ushort)bf16_rne(h);
    }
}

// ---------- L: logits MFMA, BM=128 x BN=64, 1000 blocks, XCD-swizzled (R10, validated) ----------
__global__ __launch_bounds__(256) void logits_bm128_kernel(
    const ushort* __restrict__ hbf,
    const ushort* __restrict__ Wb,
    const float* __restrict__ out_b,
    float* __restrict__ lbase, float* __restrict__ tmaxv)
{
    __shared__ __align__(16) char As[16384];
    __shared__ __align__(16) char Bs[8192];
    __shared__ float s_mv[128];
    const int tid = threadIdx.x;
    const int lane = tid & 63;
    const int wave = tid >> 6;
    const int bid = blockIdx.x;
    const int job = (bid & 7) * 125 + (bid >> 3);
    const int jx = job >> 1;
    const int jy = job & 1;
    const int row0 = jy * 128;
    const int col0 = jx * 64;

    f32x4 acc[2][4] = {};
    const int srow = tid >> 3;
    const int sch = tid & 7;

    for (int k0 = 0; k0 < 512; k0 += 64) {
        #pragma unroll
        for (int ra = 0; ra < 4; ++ra) {
            int row = ra * 32 + srow;
            const char* g = (const char*)(hbf + (long long)(row0 + row) * 512 + k0) + ((sch ^ (row & 7)) * 16);
            __builtin_amdgcn_global_load_lds(
                (const __attribute__((address_space(1))) void*)g,
                (__attribute__((address_space(3))) void*)(As + row * 128 + sch * 16), 16, 0, 0);
        }
        #pragma unroll
        for (int rb = 0; rb < 2; ++rb) {
            int row = rb * 32 + srow;
            const char* g = (const char*)(Wb + (long long)(col0 + row) * 512 + k0) + ((sch ^ (row & 7)) * 16);
            __builtin_amdgcn_global_load_lds(
                (const __attribute__((address_space(1))) void*)g,
                (__attribute__((address_space(3))) void*)(Bs + row * 128 + sch * 16), 16, 0, 0);
        }
        __syncthreads();
        #pragma unroll
        for (int k32 = 0; k32 < 64; k32 += 32) {
            bf16x8 af[2], bfr[4];
            #pragma unroll
            for (int f = 0; f < 2; ++f) {
                int rA = wave * 32 + f * 16 + (lane & 15);
                int byteA = (rA * 128 + (k32 + ((lane >> 4) << 3)) * 2) ^ ((rA & 7) << 4);
                af[f] = *(const bf16x8*)&As[byteA];
            }
            #pragma unroll
            for (int j = 0; j < 4; ++j) {
                int rB = j * 16 + (lane & 15);
                int byteB = (rB * 128 + (k32 + ((lane >> 4) << 3)) * 2) ^ ((rB & 7) << 4);
                bfr[j] = *(const bf16x8*)&Bs[byteB];
            }
            #pragma unroll
            for (int f = 0; f < 2; ++f)
                #pragma unroll
                for (int j = 0; j < 4; ++j)
                    acc[f][j] = __builtin_amdgcn_mfma_f32_16x16x32_bf16(af[f], bfr[j], acc[f][j], 0, 0, 0);
        }
        __syncthreads();
    }

    #pragma unroll
    for (int f = 0; f < 2; ++f) {
        #pragma unroll
        for (int q = 0; q < 4; ++q) {
            int r_local = wave * 32 + f * 16 + ((lane >> 4) << 2) + q;
            float* crow = lbase + (long long)(row0 + r_local) * (SLEN * (long long)VOCAB);
            float mv = -INFINITY;
            #pragma unroll
            for (int j = 0; j < 4; ++j) {
                int c = col0 + j * 16 + (lane & 15);
                float v = acc[f][j][q] + out_b[c];
                __builtin_nontemporal_store(v, &crow[c]);
                mv = fmaxf(mv, v);
            }
            #pragma unroll
            for (int m = 1; m < 16; m <<= 1) mv = fmaxf(mv, __shfl_xor(mv, m, 64));
            if ((lane & 15) == 0) s_mv[r_local] = mv;
        }
    }
    __syncthreads();
    if (tid < 128)
        tmaxv[(long long)(row0 + tid) * 512 + jx] = s_mv[tid];
}

// ---------- final argmax node for t = SLEN-1 (R10, validated) ----------
__global__ __launch_bounds__(256) void argmax_kernel(
    const float* __restrict__ tmaxv, const float* __restrict__ lbase,
    const float* __restrict__ h, const float* __restrict__ out_W,
    const float* __restrict__ out_b, const float* __restrict__ emb,
    float* __restrict__ seq, float* __restrict__ ebuf, int t)
{
    __shared__ float s_red[256];
    __shared__ int s_qt[64];
    __shared__ int s_cand[64];
    __shared__ float s_rv[64];
    __shared__ int s_cnt2[2];
    __shared__ int s_sym;
    const int b = blockIdx.x;
    const int tid = threadIdx.x;
    const int lane = tid & 63, wave = tid >> 6;
    const float* row = lbase + (long long)b * (SLEN * (long long)VOCAB);

    float v0 = tmaxv[(long long)b * 512 + tid];
    float v1 = (tid + 256 < NTILE) ? tmaxv[(long long)b * 512 + 256 + tid] : -INFINITY;
    s_red[tid] = fmaxf(v0, v1); __syncthreads();
    for (int s = 128; s > 0; s >>= 1) {
        if (tid < s) s_red[tid] = fmaxf(s_red[tid], s_red[tid + s]);
        __syncthreads();
    }
    float M = s_red[0];
    if (tid == 0) { s_cnt2[0] = 0; s_cnt2[1] = 0; }
    __syncthreads();
    if (v0 >= M - MARGIN) {
        int s = atomicAdd(&s_cnt2[0], 1);
        if (s < 64) s_qt[s] = tid;
    }
    if (v1 >= M - MARGIN) {
        int s = atomicAdd(&s_cnt2[0], 1);
        if (s < 64) s_qt[s] = tid + 256;
    }
    __syncthreads();
    int nq = min(s_cnt2[0], 64);
    for (int idx = tid; idx < nq * 64; idx += 256) {
        int c = s_qt[idx >> 6] * 64 + (idx & 63);
        if (row[c] >= M - MARGIN) {
            int s = atomicAdd(&s_cnt2[1], 1);
            if (s < 64) s_cand[s] = c;
        }
    }
    __syncthreads();
    int nc = min(s_cnt2[1], 64);
    const float* hrow = h + (long long)b * 512;
    for (int ci = wave; ci < nc; ci += 4) {
        int vv = s_cand[ci];
        const float* wrow = out_W + (long long)vv * 512;
        float s = 0.f;
        for (int k = lane; k < 512; k += 64) s = fmaf(hrow[k], wrow[k], s);
        for (int off = 32; off > 0; off >>= 1) s += __shfl_down(s, off, 64);
        if (lane == 0) s_rv[ci] = s + out_b[vv];
    }
    __syncthreads();
    if (tid == 0) {
        float bv = -INFINITY; int sym = 0x7fffffff;
        for (int ci = 0; ci < nc; ++ci) {
            float xx = s_rv[ci]; int c = s_cand[ci];
            if (xx > bv || (xx == bv && c < sym)) { bv = xx; sym = c; }
        }
        if (sym < 0 || sym >= VOCAB) sym = 0;
        seq[b * SLEN + t] = (float)sym;
        s_sym = sym;
    }
    __syncthreads();
    if (tid < EMB) ebuf[(long long)b * EMB + tid] = emb[(long long)s_sym * EMB + tid];
}

extern "C" void kernel_launch(void* const* d_in, const int* in_sizes, int n_in,
                              void* d_out, int out_size, void* d_ws, size_t ws_size,
                              hipStream_t stream) {
    const float* x     = (const float*)d_in[0];
    const float* enc_W = (const float*)d_in[1];
    const float* enc_b = (const float*)d_in[2];
    const float* in_W  = (const float*)d_in[3];
    const float* in_b  = (const float*)d_in[4];
    const float* W_ih  = (const float*)d_in[5];
    const float* W_hh  = (const float*)d_in[6];
    const float* b_ih  = (const float*)d_in[7];
    const float* b_hh  = (const float*)d_in[8];
    const float* out_W = (const float*)d_in[9];
    const float* out_b = (const float*)d_in[10];
    const float* emb   = (const float*)d_in[11];
    const float* sos   = (const float*)d_in[12];

    float* seq    = (float*)d_out;
    float* logits = (float*)d_out + BATCH * SLEN;

    char* p = (char*)d_ws;
    ushort* Wb    = (ushort*)p;  p += (size_t)VOCAB * HSZ * 2;
    float* Wcat2  = (float*)p;   p += (size_t)2048 * 576 * 4;
    float* bcat2  = (float*)p;   p += 2048 * 4;
    float* hA     = (float*)p;   p += (size_t)BATCH * HSZ * 4;
    float* hB     = (float*)p;   p += (size_t)BATCH * HSZ * 4;
    ushort* hbf   = (ushort*)p;  p += (size_t)BATCH * HSZ * 2;
    float* ebuf   = (float*)p;   p += (size_t)BATCH * EMB * 4;
    float* feat   = (float*)p;   p += (size_t)BATCH * DFEAT * 4;
    float* tmaxv  = (float*)p;   p += (size_t)BATCH * 512 * 4;
    int*   done   = (int*)p;     p += 64;

    // prologue: weights prep (+counter reset) + encoder -> input_layer -> h0
    prep_kernel<<<1024, 256, 0, stream>>>(out_W, Wb, W_ih, W_hh, b_ih, b_hh,
                                          Wcat2, bcat2, done);
    gemm_atb<64, 64, 32, 4, 4><<<dim3(DFEAT / 64, BATCH / 64), 256, 0, stream>>>(
        x, enc_W, enc_b, feat, DFEAT, BATCH, DFEAT, DIN);
    gemm_atb<64, 64, 32, 4, 4><<<dim3(HSZ / 64, BATCH / 64), 256, 0, stream>>>(
        feat, in_W, in_b, hA, HSZ, BATCH, HSZ, DFEAT);

    float* hc = hA;
    float* hn = hB;
    for (int t = 0; t < SLEN; ++t) {
        float* lbase = logits + (long long)t * VOCAB;
        if (t == 0) {
            ag2_kernel<true><<<512, 256, 0, stream>>>(
                hc, hn, Wcat2, bcat2, ebuf, sos, hbf,
                tmaxv, logits, out_W, out_b, emb, seq, done, 0, 0);
        } else {
            ag2_kernel<false><<<512, 256, 0, stream>>>(
                hc, hn, Wcat2, bcat2, ebuf, sos, hbf,
                tmaxv, logits + (long long)(t - 1) * VOCAB,
                out_W, out_b, emb, seq, done, 256 * t, t - 1);
        }
        logits_bm128_kernel<<<1000, 256, 0, stream>>>(hbf, Wb, out_b, lbase, tmaxv);
        float* tmp = hc; hc = hn; hn = tmp;
    }
    // final argmax for t = 15 (h final state is in hc after last swap)
    argmax_kernel<<<BATCH, 256, 0, stream>>>(
        tmaxv, logits + (long long)(SLEN - 1) * VOCAB, hc, out_W, out_b, emb,
        seq, ebuf, SLEN - 1);
}